// Round 1
// baseline (472.530 us; speedup 1.0000x reference)
//
#include <hip/hip_runtime.h>

#define ADAGRAD_EPS 1e-10f

typedef float f4 __attribute__((ext_vector_type(4)));

// Per-index linked lists over gradient rows: head[V], next[N] in workspace.
// (25.6M per-element atomics -> 200k atomicExch, from previous session.)

__global__ void init_head_kernel(int* __restrict__ head, int V) {
    int i4 = (blockIdx.x * blockDim.x + threadIdx.x) * 4;
    if (i4 >= V) return;
    if (i4 + 4 <= V) {
        *reinterpret_cast<int4*>(head + i4) = make_int4(-1, -1, -1, -1);
    } else {
        for (int k = i4; k < V; ++k) head[k] = -1;
    }
}

__global__ void build_lists_kernel(const int* __restrict__ idx,
                                   const int* __restrict__ vc_p,
                                   int* __restrict__ head,
                                   int* __restrict__ next) {
    int vc = *vc_p;
    int r = blockIdx.x * blockDim.x + threadIdx.x;
    if (r >= vc) return;
    int i = idx[r];
    next[r] = atomicExch(&head[i], r);
}

// One 8-lane group per vocab row v; each lane owns 2 consecutive float4s
// (32 B of the 256 B row) -> 2 outstanding VMEM ops per thread per stream.
// All single-use streams (w, m, g, outputs) use nontemporal accesses so L2
// stays reserved for the latency-critical head/next pointer chase.
__global__ __launch_bounds__(256) void apply_kernel(
        const f4* __restrict__ g4,
        const f4* __restrict__ w4,
        const f4* __restrict__ m4,
        const int* __restrict__ head,
        const int* __restrict__ next,
        const float* __restrict__ lr_p,
        f4* __restrict__ ow4,
        f4* __restrict__ om4,
        int V) {
    int t = blockIdx.x * blockDim.x + threadIdx.x;
    int v = t >> 3;
    if (v >= V) return;
    int d2 = (t & 7) << 1;
    int off = v * 16 + d2;          // f4 units; max 8M -> fits int

    int r = head[v];                // issue the branch-deciding load first
    f4 w0 = __builtin_nontemporal_load(w4 + off);
    f4 w1 = __builtin_nontemporal_load(w4 + off + 1);
    f4 m0 = __builtin_nontemporal_load(m4 + off);
    f4 m1 = __builtin_nontemporal_load(m4 + off + 1);

    if (r < 0) {                    // untouched row: plain streaming copy
        __builtin_nontemporal_store(w0, ow4 + off);
        __builtin_nontemporal_store(w1, ow4 + off + 1);
        __builtin_nontemporal_store(m0, om4 + off);
        __builtin_nontemporal_store(m1, om4 + off + 1);
        return;
    }

    f4 s10 = {0.f, 0.f, 0.f, 0.f};
    f4 s11 = s10, s20 = s10, s21 = s10;
    while (r >= 0) {
        int go = r * 16 + d2;
        f4 g0 = __builtin_nontemporal_load(g4 + go);
        f4 g1 = __builtin_nontemporal_load(g4 + go + 1);
        r = next[r];                // L2-resident pointer chase
        s10 += g0; s20 += g0 * g0;
        s11 += g1; s21 += g1 * g1;
    }

    f4 mn0 = m0 + s20;
    f4 mn1 = m1 + s21;
    __builtin_nontemporal_store(mn0, om4 + off);
    __builtin_nontemporal_store(mn1, om4 + off + 1);

    float lr = *lr_p;
    f4 wn0, wn1;
    wn0.x = w0.x - lr * s10.x / (sqrtf(mn0.x) + ADAGRAD_EPS);
    wn0.y = w0.y - lr * s10.y / (sqrtf(mn0.y) + ADAGRAD_EPS);
    wn0.z = w0.z - lr * s10.z / (sqrtf(mn0.z) + ADAGRAD_EPS);
    wn0.w = w0.w - lr * s10.w / (sqrtf(mn0.w) + ADAGRAD_EPS);
    wn1.x = w1.x - lr * s11.x / (sqrtf(mn1.x) + ADAGRAD_EPS);
    wn1.y = w1.y - lr * s11.y / (sqrtf(mn1.y) + ADAGRAD_EPS);
    wn1.z = w1.z - lr * s11.z / (sqrtf(mn1.z) + ADAGRAD_EPS);
    wn1.w = w1.w - lr * s11.w / (sqrtf(mn1.w) + ADAGRAD_EPS);
    __builtin_nontemporal_store(wn0, ow4 + off);
    __builtin_nontemporal_store(wn1, ow4 + off + 1);
}

extern "C" void kernel_launch(void* const* d_in, const int* in_sizes, int n_in,
                              void* d_out, int out_size, void* d_ws, size_t ws_size,
                              hipStream_t stream) {
    const float* g   = (const float*)d_in[0];  // [N, 64]
    const float* w   = (const float*)d_in[1];  // [V, 64]
    const float* m   = (const float*)d_in[2];  // [V, 64]
    const int*   idx = (const int*)d_in[3];    // [N]
    const float* lr  = (const float*)d_in[4];  // scalar
    const int*   vc  = (const int*)d_in[5];    // scalar

    long long ND = in_sizes[0];        // N*64
    long long VD = in_sizes[1];        // V*64
    int N = (int)(ND / 64);
    int V = (int)(VD / 64);

    float* out_w = (float*)d_out;
    float* out_m = (float*)d_out + VD;

    int* head = (int*)d_ws;            // V ints
    int* next = head + V;              // N ints

    int initThreads = (V + 3) / 4;
    init_head_kernel<<<(initThreads + 255) / 256, 256, 0, stream>>>(head, V);

    build_lists_kernel<<<(N + 255) / 256, 256, 0, stream>>>(idx, vc, head, next);

    long long apply_threads = (long long)V * 8;
    apply_kernel<<<(int)((apply_threads + 255) / 256), 256, 0, stream>>>(
        (const f4*)g, (const f4*)w, (const f4*)m,
        head, next, lr, (f4*)out_w, (f4*)out_m, V);
}